// Round 6
// baseline (830.618 us; speedup 1.0000x reference)
//
#include <hip/hip_runtime.h>
#include <cstddef>

#define NE 16384
#define NN 4096
#define BG 16
#define NT 16      // nodes per conv tile
#define ACH 8      // a-chunk size (8 chunks of 8 = 64), double-buffered

__device__ __forceinline__ float lrelu(float v){ return v >= 0.f ? v : 0.01f*v; }
__device__ __forceinline__ float sigm(float v){ return 1.f/(1.f + expf(-v)); }
__device__ __forceinline__ void fma4(float4& a, float s, const float4& w){
    a.x += s*w.x; a.y += s*w.y; a.z += s*w.z; a.w += s*w.w;
}

// ---------------- setup: W8T, h0, he, deg(dst), cnt(src) ----------------
__global__ __launch_bounds__(256) void setup_kernel(
    const float* __restrict__ x, const float* __restrict__ ea,
    const int* __restrict__ ei,
    const float* __restrict__ W0, const float* __restrict__ b0,
    const float* __restrict__ We1, const float* __restrict__ be1,
    const float* __restrict__ Wih, const float* __restrict__ Whh,
    float* __restrict__ W8T,
    float* __restrict__ h, float* __restrict__ he,
    int* __restrict__ deg, int* __restrict__ cnt)
{
    int t = blockIdx.x*256 + threadIdx.x;   // grid: 4096x256 = 1048576
    {   // he: [E,64]  lrelu(edge_attr @ We1 + be1)
        int e = t >> 6, f = t & 63;
        float v = be1[f];
        #pragma unroll
        for (int d = 0; d < 4; ++d) v += ea[e*4+d]*We1[d*64+f];
        he[t] = lrelu(v);
    }
    if (t < NN*64) {    // h0 = lrelu(x @ W0 + b0)
        int n = t >> 6, f = t & 63;
        float v = b0[f];
        #pragma unroll
        for (int d = 0; d < 3; ++d) v += x[n*3+d]*W0[d*64+f];
        h[t] = lrelu(v);
    }
    if (t < 32768) {    // W8T[k][g][8] = {Wih_r,Wih_z,Wih_n,Whh_r,Whh_z,Whh_n,0,0}
        int k = t >> 9, g = (t >> 3) & 63, j = t & 7;
        float v = 0.f;
        if (j < 3)      v = Wih[(j*64+g)*64 + k];
        else if (j < 6) v = Whh[((j-3)*64+g)*64 + k];
        W8T[t] = v;
    }
    if (t < NE) {
        atomicAdd(&deg[ei[NE + t]], 1);   // in-degree (dst) for mean aggr
        atomicAdd(&cnt[ei[t]], 1);        // out-degree (src) for edge sort
    }
}

// ---------------- exclusive scan of cnt[4096] -> offs[4097] (1 block) ----------------
__global__ __launch_bounds__(256) void scan_kernel(const int* __restrict__ cnt,
                                                   int* __restrict__ offs)
{
    __shared__ int ps[256];
    int t = threadIdx.x;
    int base = t*16;
    int loc[16];
    int s = 0;
    #pragma unroll
    for (int i = 0; i < 16; ++i) { loc[i] = s; s += cnt[base+i]; }
    ps[t] = s; __syncthreads();
    for (int off = 1; off < 256; off <<= 1) {
        int v = 0;
        if (t >= off) v = ps[t-off];
        __syncthreads();
        if (t >= off) ps[t] += v;
        __syncthreads();
    }
    int pre = (t == 0) ? 0 : ps[t-1];
    #pragma unroll
    for (int i = 0; i < 16; ++i) offs[base+i] = pre + loc[i];
    if (t == 255) offs[NN] = pre + s;
}

// ---------------- scatter: build src-sorted edge arrays ----------------
__global__ __launch_bounds__(256) void scatter_kernel(
    const int* __restrict__ ei, const int* __restrict__ offs,
    int* __restrict__ cnt,  // consumed as cursor via atomicSub
    int* __restrict__ srcs, int* __restrict__ dsts, int* __restrict__ perm)
{
    int e = blockIdx.x*256 + threadIdx.x;
    if (e >= NE) return;
    int s = ei[e], d = ei[NE + e];
    int old = atomicSub(&cnt[s], 1);
    int pos = offs[s] + old - 1;
    srcs[pos] = s; dsts[pos] = d; perm[pos] = e;
}

// ---------------- gather he rows into src-sorted order ----------------
__global__ __launch_bounds__(256) void reorder_kernel(
    const float* __restrict__ he, const int* __restrict__ perm,
    float* __restrict__ he_srt)
{
    int t = blockIdx.x*256 + threadIdx.x;   // 4096 x 256 = NE*64
    he_srt[t] = he[(size_t)perm[t>>6]*64 + (t & 63)];
}

// ---------------- inv_deg + per-graph node ranges ----------------
__global__ __launch_bounds__(256) void inv_range_kernel(
    const int* __restrict__ deg, const int* __restrict__ batch,
    float* __restrict__ inv_deg, int* __restrict__ gstart, int* __restrict__ gend)
{
    int n = blockIdx.x*256 + threadIdx.x;   // 16 blocks -> 4096
    if (n >= NN) return;
    inv_deg[n] = 1.f / fmaxf((float)deg[n], 1.f);
    int b  = batch[n];
    int bp = (n == 0)    ? -1 : batch[n-1];
    int bn = (n == NN-1) ? BG : batch[n+1];
    for (int g = bp+1; g <= b; ++g) gstart[g] = n;
    for (int g = b;   g <  bn; ++g) gend[g]   = n+1;
    if (n == 0)    for (int g = 0;   g < b;  ++g) gend[g]   = 0;
    if (n == NN-1) for (int g = b+1; g < BG; ++g) gstart[g] = NN;
}

// ---------------- fused conv: producer/consumer, LDS-instr-minimized ----------------
// R5 post-mortem: LDS pipe is the bottleneck (~80K b128-cycles/tile). Changes:
// (1) producers read h as r-PAIRS (hs2[r2][n][2]): one b128 feeds 2r x 2n x 8f
//     = 32 FMAs -> producer LDS instrs halved (4096 -> 2048 per tile);
// (2) explicit 2-stage software pipeline on the 5 loads per r2 (latency fix);
// (3) consumers widened to f8 (64 slots): 18 b128 per edge-pass vs 40;
// (4) Tb computed by consumer waves during chunk 0 (overlapped, float2 reads).
__global__ __launch_bounds__(1024) void conv_kernel(
    const float* __restrict__ h, const float* __restrict__ We2,
    const float* __restrict__ be2, const float* __restrict__ he_srt,
    const int* __restrict__ offs, const int* __restrict__ srcs,
    const int* __restrict__ dsts, float* __restrict__ agg)
{
    __shared__ float hs2[32][16][2];       // h r-pairs: [r>>1][n][r&1]   4 KB
    __shared__ float Tb [NT][64];          // 4 KB
    __shared__ float Tc [2][ACH][NT][64];  // 64 KB (double-buffered)
    __shared__ float he_s[2][128][ACH];    // 8 KB  (double-buffered) -> 80 KB
    int t  = threadIdx.x;
    int n0 = blockIdx.x * NT;

    if (t < 512) {   // stage h tile as r-pairs
        int n = t & 15, r2 = t >> 4;
        *(float2*)&hs2[r2][n][0] = *(const float2*)&h[(size_t)(n0+n)*64 + r2*2];
    }
    int ebase = offs[n0];
    int ecnt  = offs[n0+NT] - ebase;
    int eend  = ebase + ecnt;
    __syncthreads();

    // producer mapping (t < 512): (a, node-pair, f8)
    int aT  = t >> 6;            // 0..7  a' within chunk
    int nA  = ((t >> 3) & 7)*2;  // node pair nA, nA+1
    int fT8 = (t & 7) * 8;       // 8 f per thread
    // consumer mapping + persistent state (t >= 512): (slot, f8)
    int ct   = t - 512;
    int slot = ct >> 3;          // 0..63 edge slots
    int cf8  = (ct & 7) * 8;     // 8 output features per thread
    int nl0=-1, dt0=0, nl1=-1, dt1=0;
    float4 m0a={0,0,0,0}, m0b={0,0,0,0}, m1a={0,0,0,0}, m1b={0,0,0,0};
    if (t >= 512) {
        if (slot      < ecnt) { nl0 = srcs[ebase+slot]    - n0; dt0 = dsts[ebase+slot];    }
        if (slot + 64 < ecnt) { nl1 = srcs[ebase+slot+64] - n0; dt1 = dsts[ebase+slot+64]; }
    }

#define EDGE_ACC(mA, mB, nlj, row, buf_) \
    if (nlj >= 0) { \
        float4 hA = *(const float4*)&he_s[buf_][row][0]; \
        float4 hB = *(const float4*)&he_s[buf_][row][4]; \
        float he8[8] = {hA.x,hA.y,hA.z,hA.w,hB.x,hB.y,hB.z,hB.w}; \
        _Pragma("unroll") \
        for (int a_ = 0; a_ < 8; ++a_) { \
            float4 tA = *(const float4*)&Tc[buf_][a_][nlj][cf8]; \
            float4 tB = *(const float4*)&Tc[buf_][a_][nlj][cf8+4]; \
            fma4(mA, he8[a_], tA); \
            fma4(mB, he8[a_], tB); \
        } \
    }

#define CONSUME(cm) { \
    int buf_ = (cm) & 1; \
    EDGE_ACC(m0a, m0b, nl0, slot,      buf_) \
    EDGE_ACC(m1a, m1b, nl1, slot+64,   buf_) \
    for (int e = ebase + 128 + slot; e < eend; e += 64) { \
        int nl = srcs[e] - n0, dtv = dsts[e]; \
        const float* hep = he_srt + (size_t)e*64 + (cm)*ACH; \
        float4 pa = {0,0,0,0}, pb = {0,0,0,0}; \
        _Pragma("unroll") \
        for (int a_ = 0; a_ < 8; ++a_) { \
            float hv = hep[a_]; \
            float4 tA = *(const float4*)&Tc[buf_][a_][nl][cf8]; \
            float4 tB = *(const float4*)&Tc[buf_][a_][nl][cf8+4]; \
            fma4(pa, hv, tA); \
            fma4(pb, hv, tB); \
        } \
        if ((cm) == 0) { \
            float4 bA = *(const float4*)&Tb[nl][cf8]; \
            float4 bB = *(const float4*)&Tb[nl][cf8+4]; \
            pa.x += bA.x; pa.y += bA.y; pa.z += bA.z; pa.w += bA.w; \
            pb.x += bB.x; pb.y += bB.y; pb.z += bB.z; pb.w += bB.w; \
        } \
        float* ap = agg + (size_t)dtv*64 + cf8; \
        atomicAdd(ap+0, pa.x); atomicAdd(ap+1, pa.y); \
        atomicAdd(ap+2, pa.z); atomicAdd(ap+3, pa.w); \
        atomicAdd(ap+4, pb.x); atomicAdd(ap+5, pb.y); \
        atomicAdd(ap+6, pb.z); atomicAdd(ap+7, pb.w); \
    } \
}

    for (int c = 0; c < 8; ++c) {
        if (t < 512) {
            // ---- producer: T chunk c -> Tc[c&1], software-pipelined ----
            const float* Wp = We2 + (size_t)(c*ACH + aT)*4096 + fT8;
            float4 a00={0,0,0,0}, a01={0,0,0,0}, a10={0,0,0,0}, a11={0,0,0,0};
            float4 hv  = *(const float4*)&hs2[0][nA][0];
            float4 wA0 = *(const float4*)(Wp);
            float4 wA1 = *(const float4*)(Wp + 4);
            float4 wB0 = *(const float4*)(Wp + 64);
            float4 wB1 = *(const float4*)(Wp + 68);
            #pragma unroll
            for (int r2 = 0; r2 < 32; ++r2) {
                float4 hvn={0,0,0,0}, wA0n={0,0,0,0}, wA1n={0,0,0,0},
                       wB0n={0,0,0,0}, wB1n={0,0,0,0};
                if (r2 < 31) {
                    const float* Wn = Wp + (size_t)(r2+1)*128;
                    hvn  = *(const float4*)&hs2[r2+1][nA][0];
                    wA0n = *(const float4*)(Wn);
                    wA1n = *(const float4*)(Wn + 4);
                    wB0n = *(const float4*)(Wn + 64);
                    wB1n = *(const float4*)(Wn + 68);
                }
                // rA = 2*r2: hv.x (nA), hv.z (nA+1); rB = 2*r2+1: hv.y, hv.w
                fma4(a00, hv.x, wA0); fma4(a01, hv.x, wA1);
                fma4(a10, hv.z, wA0); fma4(a11, hv.z, wA1);
                fma4(a00, hv.y, wB0); fma4(a01, hv.y, wB1);
                fma4(a10, hv.w, wB0); fma4(a11, hv.w, wB1);
                hv = hvn; wA0 = wA0n; wA1 = wA1n; wB0 = wB0n; wB1 = wB1n;
            }
            int buf = c & 1;
            *(float4*)&Tc[buf][aT][nA  ][fT8]   = a00;
            *(float4*)&Tc[buf][aT][nA  ][fT8+4] = a01;
            *(float4*)&Tc[buf][aT][nA+1][fT8]   = a10;
            *(float4*)&Tc[buf][aT][nA+1][fT8+4] = a11;
        } else {
            {   // ---- consumer: stage he chunk c (consumed next phase) ----
                int le = ct >> 2, a2 = (ct & 3) * 2;
                if (ebase + le < NE)
                    *(float2*)&he_s[c&1][le][a2] =
                        *(const float2*)&he_srt[(size_t)(ebase+le)*64 + c*ACH + a2];
            }
            if (c == 0) {
                // Tb[n][f] = sum_i h[n,i]*be2[i*64+f], via r-pairs (overlapped)
                int n = ct >> 5, fp = (ct & 31) * 2;
                float t0 = 0.f, t1 = 0.f;
                #pragma unroll 8
                for (int r2 = 0; r2 < 32; ++r2) {
                    float2 hv2 = *(const float2*)&hs2[r2][n][0];
                    float2 bA  = *(const float2*)&be2[(size_t)(r2*2)*64 + fp];
                    float2 bB  = *(const float2*)&be2[(size_t)(r2*2+1)*64 + fp];
                    t0 += hv2.x*bA.x + hv2.y*bB.x;
                    t1 += hv2.x*bA.y + hv2.y*bB.y;
                }
                Tb[n][fp]   = t0;
                Tb[n][fp+1] = t1;
            } else {
                CONSUME(c-1);
            }
        }
        __syncthreads();
    }
    if (t >= 512) {
        CONSUME(7);
        // ---- scatter: one pass of atomics per edge (msg + bias) ----
        if (nl0 >= 0) {
            float4 bA = *(const float4*)&Tb[nl0][cf8];
            float4 bB = *(const float4*)&Tb[nl0][cf8+4];
            float* ap = agg + (size_t)dt0*64 + cf8;
            atomicAdd(ap+0, m0a.x+bA.x); atomicAdd(ap+1, m0a.y+bA.y);
            atomicAdd(ap+2, m0a.z+bA.z); atomicAdd(ap+3, m0a.w+bA.w);
            atomicAdd(ap+4, m0b.x+bB.x); atomicAdd(ap+5, m0b.y+bB.y);
            atomicAdd(ap+6, m0b.z+bB.z); atomicAdd(ap+7, m0b.w+bB.w);
        }
        if (nl1 >= 0) {
            float4 bA = *(const float4*)&Tb[nl1][cf8];
            float4 bB = *(const float4*)&Tb[nl1][cf8+4];
            float* ap = agg + (size_t)dt1*64 + cf8;
            atomicAdd(ap+0, m1a.x+bA.x); atomicAdd(ap+1, m1a.y+bA.y);
            atomicAdd(ap+2, m1a.z+bA.z); atomicAdd(ap+3, m1a.w+bA.w);
            atomicAdd(ap+4, m1b.x+bB.x); atomicAdd(ap+5, m1b.y+bB.y);
            atomicAdd(ap+6, m1b.z+bB.z); atomicAdd(ap+7, m1b.w+bB.w);
        }
    }
#undef CONSUME
#undef EDGE_ACC
}

// ---------------- node kernel: m, gi, gh + GRU; thread = (node, gate-col) ----
__global__ __launch_bounds__(512) void node_kernel(
    const float* __restrict__ W8T, const float* __restrict__ root,
    const float* __restrict__ conv_b, const float* __restrict__ inv_deg,
    const float* __restrict__ bih, const float* __restrict__ bhh,
    float* __restrict__ h, float* __restrict__ agg)
{
    __shared__ float hs[8][64];
    __shared__ float ms[8][64];
    int t = threadIdx.x;
    int n = t >> 6, g = t & 63;
    int gn = blockIdx.x*8 + n;
    hs[n][g] = h[(size_t)gn*64 + g];
    __syncthreads();
    {   // m = lrelu(agg*inv_deg + h@root + conv_b)
        size_t ix = (size_t)gn*64 + g;
        float v = agg[ix]*inv_deg[gn] + conv_b[g];
        agg[ix] = 0.f;                     // ready for next iteration's conv
        #pragma unroll 8
        for (int k = 0; k < 64; ++k) v += hs[n][k]*root[k*64 + g];
        ms[n][g] = lrelu(v);
    }
    __syncthreads();

    float ir=0.f, iz=0.f, in_=0.f, hr=0.f, hz=0.f, hn=0.f;
    const float* Wp = W8T + (size_t)g*8;
    #pragma unroll 8
    for (int k = 0; k < 64; ++k) {
        float am = ms[n][k], ah = hs[n][k];
        float4 w0 = *(const float4*)(Wp + (size_t)k*512);
        float4 w1 = *(const float4*)(Wp + (size_t)k*512 + 4);
        ir  += am*w0.x; iz += am*w0.y; in_ += am*w0.z;
        hr  += ah*w0.w; hz += ah*w1.x; hn  += ah*w1.y;
    }
    float r  = sigm(ir + bih[g]      + hr + bhh[g]);
    float z  = sigm(iz + bih[64+g]   + hz + bhh[64+g]);
    float nn = tanhf(in_ + bih[128+g] + r*(hn + bhh[128+g]));
    h[(size_t)gn*64 + g] = (1.f - z)*nn + z*hs[n][g];
}

// ---------------- finale ----------------
__device__ __forceinline__ float q_val(const float* lbih, const float* lbhh, int g)
{
    float gi = lbih[g]     + lbhh[g];
    float gg = lbih[128+g] + lbhh[128+g];
    float go = lbih[192+g] + lbhh[192+g];
    return sigm(go)*tanhf(sigm(gi)*tanhf(gg));   // hl0=cl0=q_star0=0
}

__global__ __launch_bounds__(256) void e_kernel(
    const float* __restrict__ h, const float* __restrict__ lbih,
    const float* __restrict__ lbhh, float* __restrict__ e)
{
    __shared__ float qs[64];
    int t = threadIdx.x;
    if (t < 64) qs[t] = q_val(lbih, lbhh, t);
    __syncthreads();
    int w = t >> 6, f = t & 63;
    int n = blockIdx.x*4 + w;
    float p = h[(size_t)n*64 + f]*qs[f];
    #pragma unroll
    for (int off = 32; off; off >>= 1) p += __shfl_xor(p, off);
    if (f == 0) e[n] = p;
}

__global__ __launch_bounds__(1024) void pool_kernel(
    const float* __restrict__ h, float* __restrict__ e,
    const int* __restrict__ gstart, const int* __restrict__ gend,
    const float* __restrict__ lbih, const float* __restrict__ lbhh,
    const float* __restrict__ Wout, const float* __restrict__ bout,
    float* __restrict__ out)
{
    __shared__ float red[1024];
    __shared__ float rp[64];
    __shared__ float sval;
    int g = blockIdx.x, t = threadIdx.x;
    int s = gstart[g], en = gend[g];

    float mx = -1e30f;
    for (int n = s+t; n < en; n += 1024) mx = fmaxf(mx, e[n]);
    red[t] = mx; __syncthreads();
    for (int st = 512; st; st >>= 1) { if (t < st) red[t] = fmaxf(red[t], red[t+st]); __syncthreads(); }
    if (t == 0) sval = red[0];
    __syncthreads();
    float lmx = sval;
    __syncthreads();

    float sm = 0.f;
    for (int n = s+t; n < en; n += 1024) { float a = expf(e[n]-lmx); e[n] = a; sm += a; }
    red[t] = sm; __syncthreads();
    for (int st = 512; st; st >>= 1) { if (t < st) red[t] += red[t+st]; __syncthreads(); }
    if (t == 0) sval = (red[0] > 0.f) ? 1.f/red[0] : 0.f;
    __syncthreads();
    float inv_asum = sval;
    __syncthreads();

    int w = t >> 6, f = t & 63;
    float racc = 0.f;
    for (int n = s+w; n < en; n += 16) racc += e[n]*h[(size_t)n*64 + f];
    red[t] = racc; __syncthreads();
    if (w == 0) {
        float a = 0.f;
        #pragma unroll
        for (int i = 0; i < 16; ++i) a += red[i*64 + f];
        rp[f] = a*inv_asum;
    }
    __syncthreads();

    if (t < 64) {
        float qv = q_val(lbih, lbhh, t);
        float p0 = qv*Wout[t*2]   + rp[t]*Wout[(64+t)*2];
        float p1 = qv*Wout[t*2+1] + rp[t]*Wout[(64+t)*2+1];
        #pragma unroll
        for (int off = 32; off; off >>= 1) { p0 += __shfl_xor(p0, off); p1 += __shfl_xor(p1, off); }
        if (t == 0) { out[g*2] = p0 + bout[0]; out[g*2+1] = p1 + bout[1]; }
    }
}

extern "C" void kernel_launch(void* const* d_in, const int* in_sizes, int n_in,
                              void* d_out, int out_size, void* d_ws, size_t ws_size,
                              hipStream_t stream)
{
    const float* x      = (const float*)d_in[0];
    const float* ea     = (const float*)d_in[1];
    const int*   ei     = (const int*)  d_in[2];
    const int*   batch  = (const int*)  d_in[3];
    const float* W0     = (const float*)d_in[4];
    const float* b0     = (const float*)d_in[5];
    const float* We1    = (const float*)d_in[6];
    const float* be1    = (const float*)d_in[7];
    const float* We2    = (const float*)d_in[8];
    const float* be2    = (const float*)d_in[9];
    const float* root   = (const float*)d_in[10];
    const float* conv_b = (const float*)d_in[11];
    const float* Wih    = (const float*)d_in[12];
    const float* Whh    = (const float*)d_in[13];
    const float* bih    = (const float*)d_in[14];
    const float* bhh    = (const float*)d_in[15];
    const float* lbih   = (const float*)d_in[18];
    const float* lbhh   = (const float*)d_in[19];
    const float* Wout   = (const float*)d_in[20];
    const float* bout   = (const float*)d_in[21];
    float* out = (float*)d_out;

    float* W = (float*)d_ws;
    size_t off = 0;
    float* h       = W + off; off += (size_t)NN*64;
    float* he      = W + off; off += (size_t)NE*64;
    float* he_srt  = W + off; off += (size_t)NE*64;
    float* agg     = W + off; off += (size_t)NN*64;
    float* W8T     = W + off; off += 32768;
    float* inv_deg = W + off; off += NN;
    float* e       = W + off; off += NN;
    int*   deg     = (int*)(W + off); off += NN;   // deg+cnt contiguous: one memset
    int*   cnt     = (int*)(W + off); off += NN;
    int*   offs    = (int*)(W + off); off += NN+1;
    int*   srcs    = (int*)(W + off); off += NE;
    int*   dsts    = (int*)(W + off); off += NE;
    int*   perm    = (int*)(W + off); off += NE;
    int*   gstart  = (int*)(W + off); off += BG;
    int*   gend    = (int*)(W + off); off += BG;

    hipMemsetAsync(deg, 0, 2*NN*sizeof(int), stream);
    hipMemsetAsync(agg, 0, (size_t)NN*64*sizeof(float), stream);
    setup_kernel<<<4096, 256, 0, stream>>>(x, ea, ei, W0, b0, We1, be1, Wih, Whh,
                                           W8T, h, he, deg, cnt);
    scan_kernel<<<1, 256, 0, stream>>>(cnt, offs);
    scatter_kernel<<<64, 256, 0, stream>>>(ei, offs, cnt, srcs, dsts, perm);
    reorder_kernel<<<4096, 256, 0, stream>>>(he, perm, he_srt);
    inv_range_kernel<<<16, 256, 0, stream>>>(deg, batch, inv_deg, gstart, gend);

    for (int it = 0; it < 6; ++it) {
        conv_kernel<<<NN/NT, 1024, 0, stream>>>(h, We2, be2, he_srt,
                                                offs, srcs, dsts, agg);
        node_kernel<<<NN/8, 512, 0, stream>>>(W8T, root, conv_b,
                                              inv_deg, bih, bhh, h, agg);
    }

    e_kernel<<<NN/4, 256, 0, stream>>>(h, lbih, lbhh, e);
    pool_kernel<<<BG, 1024, 0, stream>>>(h, e, gstart, gend, lbih, lbhh, Wout, bout, out);
}